// Round 4
// baseline (3792556.250 us; speedup 1.0000x reference)
//
#include <hip/hip_runtime.h>
#include <hip/hip_bf16.h>
#include <stdint.h>

// TextRNN: 2-layer tanh RNN. B=128,T=512,H=512,E=256,V=32000.
//   k_init : zero h-state double buffers + group flags (ws)
//   k_cw   : CW[v][j] = C[v]@W_ax.T (bf16, 32MB ws) -- x-proj hoisted out of the scan
//   k_scan : 8 groups (16 batch rows) x 8 members (64 cols). Weights bf16 in LDS.
//            Skewed: step t computes h0(t) and h1(t-1); split flags f0/f1, one combined poll.
//            CO-XCD FAST PATH: if all 8 members share an XCD (HW_REG_XCC_ID consensus),
//            state+flags use sc0-only (XCD-local L2, ~250cy) instead of sc0 sc1 (MALL).
//   k_out  : out = h1_final @ W_out.T + b_out
//
// R3 post-mortem: per-barrier cost 4.0us unchanged vs R2 -> LLC round trips + cw gather
// serialized inside the poll's vmcnt(0). Fixes: L2-scope protocol, cw prefetch at loop
// bottom, single-wave store+drain+signal per state tensor.

#define VOCAB 32000
#define EMB   256
#define HID   512
#define BATCH 128
#define SEQ   512
#define GBUF_ELEMS 8192   // per-group h slice: 512 cols x 16 rows bf16
#define GHALF (8 * GBUF_ELEMS)   // parity stride (elems)

typedef __attribute__((ext_vector_type(8))) short bf16x8;
typedef __attribute__((ext_vector_type(4))) float f32x4;

__device__ inline short f2bf(float f) {
  union { float f; uint32_t u; } v; v.f = f;
  uint32_t u = v.u;
  uint32_t r = (u + 0x7FFFu + ((u >> 16) & 1u)) >> 16;
  return (short)r;
}
__device__ inline float bf2f(unsigned short s) {
  union { uint32_t u; float f; } v; v.u = ((uint32_t)s) << 16;
  return v.f;
}
__device__ inline bf16x8 cvt8(f32x4 x0, f32x4 x1) {
  bf16x8 r;
  r[0]=f2bf(x0[0]); r[1]=f2bf(x0[1]); r[2]=f2bf(x0[2]); r[3]=f2bf(x0[3]);
  r[4]=f2bf(x1[0]); r[5]=f2bf(x1[1]); r[6]=f2bf(x1[2]); r[7]=f2bf(x1[3]);
  return r;
}
__device__ inline f32x4 mfma16(bf16x8 a, bf16x8 b, f32x4 c) {
  return __builtin_amdgcn_mfma_f32_16x16x32_bf16(a, b, c, 0, 0, 0);
}
__device__ inline float fast_tanh(float x) {
  x = fminf(30.f, fmaxf(-30.f, x));
  float e = __expf(2.f * x);
  return (e - 1.f) * __builtin_amdgcn_rcpf(e + 1.f);
}

// dual-path LLC/L2 primitives -------------------------------------------------
__device__ inline void st16(unsigned short* p, bf16x8 v, bool fast) {
  if (fast) asm volatile("global_store_dwordx4 %0, %1, off sc0"     :: "v"(p), "v"(v) : "memory");
  else      asm volatile("global_store_dwordx4 %0, %1, off sc0 sc1" :: "v"(p), "v"(v) : "memory");
}
__device__ inline void st_flag(unsigned* p, unsigned v, bool fast) {
  if (fast) asm volatile("global_store_dword %0, %1, off sc0"     :: "v"(p), "v"(v) : "memory");
  else      asm volatile("global_store_dword %0, %1, off sc0 sc1" :: "v"(p), "v"(v) : "memory");
}
// combined poll: lanes 0-7 -> f0[0..7], lanes 8-15 -> f1[0..7] (at fl+16)
__device__ inline void poll2(const unsigned* fl, unsigned target, bool fast) {
  const int lane = threadIdx.x & 63;
  bool ok = (lane >= 16);
  const unsigned* fp = fl + ((lane < 8) ? lane : (8 + lane));
  unsigned v = 0;
  int guard = 0;
  while (true) {
    if (!ok) {
      if (fast) asm volatile("global_load_dword %0, %1, off sc0\n\ts_waitcnt vmcnt(0)"
                             : "=v"(v) : "v"(fp) : "memory");
      else      asm volatile("global_load_dword %0, %1, off sc0 sc1\n\ts_waitcnt vmcnt(0)"
                             : "=v"(v) : "v"(fp) : "memory");
      ok = (v >= target);
    }
    if (__ballot(ok) == ~0ull) break;
    __builtin_amdgcn_s_sleep(1);
    if (++guard > 200000) break;   // fail visibly, never hang the harness
  }
}

__global__ void k_init(unsigned* __restrict__ p, int n) {
  int i = blockIdx.x * 256 + threadIdx.x;
  if (i < n) p[i] = 0u;
}

// ---- CW = C @ W_ax.T  (M=32000, N=512, K=256), bf16 out ----
__global__ void __launch_bounds__(256) k_cw(const float* __restrict__ C,
                                            const float* __restrict__ Wax,
                                            unsigned short* __restrict__ CW) {
  const int tid = threadIdx.x, lane = tid & 63, wv = tid >> 6;
  const int l15 = lane & 15, l4 = lane >> 4;
  const int row = blockIdx.x * 64 + wv * 16 + l15;
  bf16x8 a[8];
  const float* crow = C + (size_t)row * EMB;
#pragma unroll
  for (int s = 0; s < 8; ++s) {
    const f32x4* p = (const f32x4*)(crow + s * 32 + l4 * 8);
    a[s] = cvt8(p[0], p[1]);
  }
  const int row_o_base = blockIdx.x * 64 + wv * 16 + l4 * 4;
  for (int ct = 0; ct < 8; ++ct) {
    f32x4 acc[4];
#pragma unroll
    for (int nf = 0; nf < 4; ++nf) acc[nf] = (f32x4){0.f, 0.f, 0.f, 0.f};
#pragma unroll
    for (int s = 0; s < 8; ++s) {
#pragma unroll
      for (int nf = 0; nf < 4; ++nf) {
        int col = ct * 64 + nf * 16 + l15;
        const f32x4* bp = (const f32x4*)(Wax + (size_t)col * EMB + s * 32 + l4 * 8);
        bf16x8 b = cvt8(bp[0], bp[1]);
        acc[nf] = mfma16(a[s], b, acc[nf]);
      }
    }
#pragma unroll
    for (int nf = 0; nf < 4; ++nf) {
      int col = ct * 64 + nf * 16 + l15;
#pragma unroll
      for (int r = 0; r < 4; ++r)
        CW[(size_t)(row_o_base + r) * HID + col] = (unsigned short)f2bf(acc[nf][r]);
    }
  }
}

// ---- the recurrent scan ----
__global__ void __launch_bounds__(256, 1) k_scan(
    const int* __restrict__ X, const float* __restrict__ Waa, const float* __restrict__ Wal,
    const float* __restrict__ ba, const unsigned short* __restrict__ CW,
    unsigned short* __restrict__ h0buf, unsigned short* __restrict__ h1buf,
    unsigned* __restrict__ flags) {
  extern __shared__ unsigned short lds[];
  unsigned short* ldsWaa = lds;              // [64][512] bf16, 16B-unit swizzled
  unsigned short* ldsWal = lds + 64 * 512;
  unsigned short* sh     = lds + 2 * 64 * 512;  // 2048 shorts: [h0 1024][h1 1024]
  const int tid = threadIdx.x, lane = tid & 63, wv = tid >> 6;
  const int l15 = lane & 15, l4 = lane >> 4;
  const int g = blockIdx.x & 7, mem = blockIdx.x >> 3;  // group -> same XCD (b%8 heuristic)
  const int colslice = mem * 64;
  unsigned* fl = flags + g * 32;   // [0..7]=f0  [8..15]=xcc handshake  [16..23]=f1

  // publish own XCC id (LLC) before staging weights; poll after staging.
  unsigned myxcc;
  asm volatile("s_getreg_b32 %0, hwreg(HW_REG_XCC_ID)" : "=s"(myxcc));
  if (tid == 0)
    asm volatile("global_store_dword %0, %1, off sc0 sc1"
                 :: "v"(fl + 8 + mem), "v"(myxcc + 1u) : "memory");

  // stage weight slices (rows colslice..colslice+63) f32 -> bf16 LDS, swizzled
  for (int c = tid; c < 64 * 64; c += 256) {
    int row = c >> 6, u = c & 63, us = u ^ (row & 7);
    {
      const f32x4* p = (const f32x4*)(Waa + (size_t)(colslice + row) * HID + u * 8);
      *(bf16x8*)(ldsWaa + row * 512 + us * 8) = cvt8(p[0], p[1]);
    }
    {
      const f32x4* p = (const f32x4*)(Wal + (size_t)(colslice + row) * HID + u * 8);
      *(bf16x8*)(ldsWal + row * 512 + us * 8) = cvt8(p[0], p[1]);
    }
  }

  // XCD consensus -> fast (L2) vs slow (LLC) protocol. Group-uniform either way.
  bool fast;
  {
    const unsigned* xp = fl + 8 + (lane & 7);
    unsigned v = 0; bool ok = (lane >= 8); int guard = 0;
    while (true) {
      if (!ok) {
        asm volatile("global_load_dword %0, %1, off sc0 sc1\n\ts_waitcnt vmcnt(0)"
                     : "=v"(v) : "v"(xp) : "memory");
        ok = (v != 0u);
      }
      if (__ballot(ok) == ~0ull) break;
      __builtin_amdgcn_s_sleep(1);
      if (++guard > 1000000) break;
    }
    bool eq = (lane >= 8) || (v == myxcc + 1u);
    fast = (__ballot(eq) == ~0ull);
  }

  const int jloc = colslice + wv * 16 + l15;   // this lane's output col
  const float bav = ba[jloc];
  const int wrow = wv * 16 + l15;
  const int wbase = wrow * 512;
  const int wswz = wrow & 7;
  const int aoff = l4 * 128 + l15 * 8;
  const int shoff = (wrow >> 3) * 128 + (wrow & 7);
  unsigned short* h0g = h0buf + g * GBUF_ELEMS;
  unsigned short* h1g = h1buf + g * GBUF_ELEMS;
  const int brow0 = g * 16 + l4 * 4;
  __syncthreads();

  // prefetch cw(0) (plain cached loads; drained by the first poll's vmcnt(0))
  unsigned cwv[4];
#pragma unroll
  for (int r = 0; r < 4; ++r) {
    int idx = X[(size_t)(brow0 + r) * SEQ + 0];
    const unsigned short* cp = CW + (size_t)idx * HID + jloc;
    asm volatile("global_load_ushort %0, %1, off" : "=v"(cwv[r]) : "v"(cp) : "memory");
  }

#define LOAD16(arr, base, FLAGS)                                                  \
  _Pragma("unroll") for (int s = 0; s < 16; ++s)                                  \
    asm volatile("global_load_dwordx4 %0, %1, off " FLAGS                         \
                 : "=v"(arr[s]) : "v"((base) + s * 1024) : "memory");

  for (int t = 0; t <= SEQ; ++t) {
    const int par = t & 1, parp = par ^ 1;

    poll2(fl, (unsigned)t, fast);   // f0>=t and f1>=t (drains cw prefetch too)

    bf16x8 a0[16], a2[16];
    const char* pa0 = (const char*)(h0g + parp * GHALF + aoff);
    const char* pa2 = (const char*)(h1g + par  * GHALF + aoff);
    if (fast) { LOAD16(a0, pa0, "sc0")     LOAD16(a2, pa2, "sc0") }
    else      { LOAD16(a0, pa0, "sc0 sc1") LOAD16(a2, pa2, "sc0 sc1") }

    asm volatile("s_waitcnt vmcnt(16)" ::: "memory");   // a0 complete
    __builtin_amdgcn_sched_barrier(0);

    f32x4 acc0  = (f32x4){0.f, 0.f, 0.f, 0.f};
    f32x4 acc1  = (f32x4){0.f, 0.f, 0.f, 0.f};
    f32x4 acc1b = (f32x4){0.f, 0.f, 0.f, 0.f};
    if (t < SEQ) {
#pragma unroll
      for (int s = 0; s < 16; ++s) {
        bf16x8 b = *(const bf16x8*)(ldsWaa + wbase + (((s * 4 + l4) ^ wswz) * 8));
        acc0 = mfma16(a0[s], b, acc0);
      }
    }
    if (t >= 1) {
#pragma unroll
      for (int s = 0; s < 16; ++s) {
        bf16x8 b = *(const bf16x8*)(ldsWal + wbase + (((s * 4 + l4) ^ wswz) * 8));
        acc1 = mfma16(a0[s], b, acc1);
      }
    }
    asm volatile("s_waitcnt vmcnt(0)" ::: "memory");    // a2 complete
    __builtin_amdgcn_sched_barrier(0);
    if (t >= 1) {
#pragma unroll
      for (int s = 0; s < 16; ++s) {
        bf16x8 b = *(const bf16x8*)(ldsWaa + wbase + (((s * 4 + l4) ^ wswz) * 8));
        acc1b = mfma16(a2[s], b, acc1b);
      }
    }

    // tanh + LDS pack (A-frag layout within this member's 64-col slice)
    if (t < SEQ) {
#pragma unroll
      for (int r = 0; r < 4; ++r) {
        float h = fast_tanh(acc0[r] + bf2f((unsigned short)cwv[r]) + bav);
        sh[shoff + (l4 * 4 + r) * 8] = (unsigned short)f2bf(h);
      }
    }
    if (t >= 1) {
#pragma unroll
      for (int r = 0; r < 4; ++r) {
        float h = fast_tanh(acc1[r] + acc1b[r] + bav);
        sh[1024 + shoff + (l4 * 4 + r) * 8] = (unsigned short)f2bf(h);
      }
    }
    __syncthreads();

    // single-wave store + drain + signal per tensor: wave0 -> h0/f0, wave1 -> h1/f1
    if (wv == 0) {
      if (t < SEQ) {
        bf16x8 v0 = *(const bf16x8*)(sh + lane * 8);
        bf16x8 v1 = *(const bf16x8*)(sh + 512 + lane * 8);
        unsigned short* d = h0g + par * GHALF + colslice * 16 + lane * 8;
        st16(d, v0, fast); st16(d + 512, v1, fast);
      }
      asm volatile("s_waitcnt vmcnt(0)" ::: "memory");
      if (lane == 0) st_flag(fl + mem, (unsigned)(t + 1), fast);
    } else if (wv == 1) {
      if (t >= 1) {
        bf16x8 v0 = *(const bf16x8*)(sh + 1024 + lane * 8);
        bf16x8 v1 = *(const bf16x8*)(sh + 1536 + lane * 8);
        unsigned short* d = h1g + parp * GHALF + colslice * 16 + lane * 8;
        st16(d, v0, fast); st16(d + 512, v1, fast);
      }
      asm volatile("s_waitcnt vmcnt(0)" ::: "memory");
      if (lane == 0) st_flag(fl + 16 + mem, (unsigned)(t + 1), fast);
    }

    // prefetch cw(t+1) AFTER signal: overlaps next barrier, drained by next poll
    if (t + 1 < SEQ) {
#pragma unroll
      for (int r = 0; r < 4; ++r) {
        int idx = X[(size_t)(brow0 + r) * SEQ + (t + 1)];
        const unsigned short* cp = CW + (size_t)idx * HID + jloc;
        asm volatile("global_load_ushort %0, %1, off" : "=v"(cwv[r]) : "v"(cp) : "memory");
      }
    }
  }
#undef LOAD16
}

// ---- out = h1_final @ W_out.T + b_out  (M=128, N=32000, K=512) ----
__global__ void __launch_bounds__(256) k_out(const float* __restrict__ Wout,
                                             const float* __restrict__ bout,
                                             const unsigned short* __restrict__ h1buf,
                                             float* __restrict__ out) {
  const int tid = threadIdx.x, lane = tid & 63, wv = tid >> 6;
  const int l15 = lane & 15, l4 = lane >> 4;
  const int col = blockIdx.x * 64 + wv * 16 + l15;
  const float bo = bout[col];
  f32x4 acc[8];
#pragma unroll
  for (int rt = 0; rt < 8; ++rt) acc[rt] = (f32x4){0.f, 0.f, 0.f, 0.f};
  const unsigned short* h1p1 = h1buf + GHALF;  // parity-1 = final h1(511)
  const int aoff = l4 * 128 + l15 * 8;
#pragma unroll 4
  for (int s = 0; s < 16; ++s) {
    const f32x4* bp = (const f32x4*)(Wout + (size_t)col * HID + s * 32 + l4 * 8);
    bf16x8 b = cvt8(bp[0], bp[1]);
#pragma unroll
    for (int rt = 0; rt < 8; ++rt) {
      bf16x8 a = *(const bf16x8*)(h1p1 + rt * GBUF_ELEMS + aoff + s * 512);
      acc[rt] = mfma16(a, b, acc[rt]);
    }
  }
#pragma unroll
  for (int rt = 0; rt < 8; ++rt) {
#pragma unroll
    for (int r = 0; r < 4; ++r) {
      int row = rt * 16 + l4 * 4 + r;
      out[(size_t)row * VOCAB + col] = acc[rt][r] + bo;
    }
  }
}

extern "C" void kernel_launch(void* const* d_in, const int* in_sizes, int n_in,
                              void* d_out, int out_size, void* d_ws, size_t ws_size,
                              hipStream_t stream) {
  const int*   X    = (const int*)d_in[0];
  const float* C    = (const float*)d_in[1];
  const float* Wax  = (const float*)d_in[2];
  const float* Waa  = (const float*)d_in[3];
  const float* Wal  = (const float*)d_in[4];
  const float* ba   = (const float*)d_in[5];
  const float* Wout = (const float*)d_in[6];
  const float* bout = (const float*)d_in[7];
  float* out = (float*)d_out;
  char* ws = (char*)d_ws;
  (void)in_sizes; (void)n_in; (void)out_size;

  const size_t cw_bytes = (size_t)VOCAB * HID * 2;          // 32,768,000
  const size_t h_bytes  = 2ull * GHALF * 2;                 // 262,144 (2 parities)
  const size_t off_h0 = cw_bytes;
  const size_t off_h1 = off_h0 + h_bytes;
  const size_t off_fl = off_h1 + h_bytes;
  const size_t fl_bytes = 8 * 32 * 4;                       // 1 KB
  if (ws_size < off_fl + fl_bytes) return;

  unsigned short* CWp = (unsigned short*)(ws);
  unsigned short* h0  = (unsigned short*)(ws + off_h0);
  unsigned short* h1  = (unsigned short*)(ws + off_h1);
  unsigned*       fl  = (unsigned*)(ws + off_fl);

  const int zero_words = (int)((2 * h_bytes + fl_bytes) / 4);
  hipLaunchKernelGGL(k_init, dim3((zero_words + 255) / 256), dim3(256), 0, stream,
                     (unsigned*)(ws + off_h0), zero_words);
  hipLaunchKernelGGL(k_cw, dim3(VOCAB / 64), dim3(256), 0, stream, C, Wax, CWp);
  hipFuncSetAttribute((const void*)k_scan, hipFuncAttributeMaxDynamicSharedMemorySize, 135168);
  hipLaunchKernelGGL(k_scan, dim3(64), dim3(256), 135168, stream,
                     X, Waa, Wal, ba, CWp, h0, h1, fl);
  hipLaunchKernelGGL(k_out, dim3(VOCAB / 64), dim3(256), 0, stream, Wout, bout, h1, out);
}

// Round 6
// 2039.751 us; speedup vs baseline: 1859.3233x; 1859.3233x over previous
//
#include <hip/hip_runtime.h>
#include <hip/hip_bf16.h>
#include <stdint.h>

// TextRNN: 2-layer tanh RNN. B=128,T=512,H=512,E=256,V=32000.
// R6: wave-decoupled scan, MALL-only (sc0 sc1) protocol — R5's risky machinery removed.
//   waves 0,1: h0 recurrence (2 col-tiles each). waves 2,3: h1 (one step behind).
//   Per-wave flags (16 per family), NSLOT=4 slot rotation (2-step slack), per-wave
//   LDS pack -> one coalesced dwordx4 store per lane. No __syncthreads in loop.
// R5 post-mortem: core-dump from one of {buffer_inv, probe, scalar stores} — all removed.

#define VOCAB 32000
#define EMB   256
#define HID   512
#define BATCH 128
#define SEQ   512
#define SLOT  8192          // one time-slot: 64 units * 16 rows * 8 shorts
#define NSLOT 4

typedef __attribute__((ext_vector_type(8))) short bf16x8;
typedef __attribute__((ext_vector_type(4))) float f32x4;

__device__ inline short f2bf(float f) {
  union { float f; uint32_t u; } v; v.f = f;
  uint32_t u = v.u;
  uint32_t r = (u + 0x7FFFu + ((u >> 16) & 1u)) >> 16;
  return (short)r;
}
__device__ inline float bf2f(unsigned short s) {
  union { uint32_t u; float f; } v; v.u = ((uint32_t)s) << 16;
  return v.f;
}
__device__ inline bf16x8 cvt8(f32x4 x0, f32x4 x1) {
  bf16x8 r;
  r[0]=f2bf(x0[0]); r[1]=f2bf(x0[1]); r[2]=f2bf(x0[2]); r[3]=f2bf(x0[3]);
  r[4]=f2bf(x1[0]); r[5]=f2bf(x1[1]); r[6]=f2bf(x1[2]); r[7]=f2bf(x1[3]);
  return r;
}
__device__ inline f32x4 mfma16(bf16x8 a, bf16x8 b, f32x4 c) {
  return __builtin_amdgcn_mfma_f32_16x16x32_bf16(a, b, c, 0, 0, 0);
}
__device__ inline float fast_tanh(float x) {
  x = fminf(30.f, fmaxf(-30.f, x));
  float e = __expf(2.f * x);
  return (e - 1.f) * __builtin_amdgcn_rcpf(e + 1.f);
}

#define VMCNT0  asm volatile("s_waitcnt vmcnt(0)" ::: "memory")
#define VMCNT16 asm volatile("s_waitcnt vmcnt(16)" ::: "memory")
#define LGKM0   asm volatile("s_waitcnt lgkmcnt(0)" ::: "memory")
#define SCHED0  __builtin_amdgcn_sched_barrier(0)

__device__ inline void st16(unsigned short* p, bf16x8 v) {
  asm volatile("global_store_dwordx4 %0, %1, off sc0 sc1" :: "v"(p), "v"(v) : "memory");
}
__device__ inline void sig(unsigned* p, unsigned v) {
  asm volatile("global_store_dword %0, %1, off sc0 sc1" :: "v"(p), "v"(v) : "memory");
}
// lanes 0-15: f0[lane] >= t0 ; lanes 16-31: f1[lane-16] >= t1 ; others idle
__device__ inline void poll2(const unsigned* f0, const unsigned* f1,
                             unsigned t0, unsigned t1) {
  const int lane = threadIdx.x & 63;
  bool ok = (lane >= 32);
  const unsigned* fp = (lane < 16) ? (f0 + lane) : (f1 + (lane - 16));
  const unsigned tgt = (lane < 16) ? t0 : t1;
  unsigned v = 0; int guard = 0;
  while (true) {
    if (!ok) {
      asm volatile("global_load_dword %0, %1, off sc0 sc1\n\ts_waitcnt vmcnt(0)"
                   : "=v"(v) : "v"(fp) : "memory");
      ok = (v >= tgt);
    }
    if (__ballot(ok) == ~0ull) break;
    __builtin_amdgcn_s_sleep(1);
    if (++guard > 30000) break;   // fail visibly, never hang the harness
  }
}

__global__ void k_init(unsigned* __restrict__ p, int n) {
  int i = blockIdx.x * 256 + threadIdx.x;
  if (i < n) p[i] = 0u;
}

// ---- CW = C @ W_ax.T  (M=32000, N=512, K=256), bf16 out ----
__global__ void __launch_bounds__(256) k_cw(const float* __restrict__ C,
                                            const float* __restrict__ Wax,
                                            unsigned short* __restrict__ CW) {
  const int tid = threadIdx.x, lane = tid & 63, wv = tid >> 6;
  const int l15 = lane & 15, l4 = lane >> 4;
  const int row = blockIdx.x * 64 + wv * 16 + l15;
  bf16x8 a[8];
  const float* crow = C + (size_t)row * EMB;
#pragma unroll
  for (int s = 0; s < 8; ++s) {
    const f32x4* p = (const f32x4*)(crow + s * 32 + l4 * 8);
    a[s] = cvt8(p[0], p[1]);
  }
  const int row_o_base = blockIdx.x * 64 + wv * 16 + l4 * 4;
  for (int ct = 0; ct < 8; ++ct) {
    f32x4 acc[4];
#pragma unroll
    for (int nf = 0; nf < 4; ++nf) acc[nf] = (f32x4){0.f, 0.f, 0.f, 0.f};
#pragma unroll
    for (int s = 0; s < 8; ++s) {
#pragma unroll
      for (int nf = 0; nf < 4; ++nf) {
        int col = ct * 64 + nf * 16 + l15;
        const f32x4* bp = (const f32x4*)(Wax + (size_t)col * EMB + s * 32 + l4 * 8);
        bf16x8 b = cvt8(bp[0], bp[1]);
        acc[nf] = mfma16(a[s], b, acc[nf]);
      }
    }
#pragma unroll
    for (int nf = 0; nf < 4; ++nf) {
      int col = ct * 64 + nf * 16 + l15;
#pragma unroll
      for (int r = 0; r < 4; ++r)
        CW[(size_t)(row_o_base + r) * HID + col] = (unsigned short)f2bf(acc[nf][r]);
    }
  }
}

// ---- the recurrent scan ----
__global__ void __launch_bounds__(256, 1) k_scan(
    const int* __restrict__ X, const float* __restrict__ Waa, const float* __restrict__ Wal,
    const float* __restrict__ ba, const unsigned short* __restrict__ CW,
    unsigned short* __restrict__ h0buf, unsigned short* __restrict__ h1buf,
    unsigned* __restrict__ flags) {
  extern __shared__ unsigned short lds[];
  unsigned short* ldsWaa = lds;                 // [64][512] bf16, 16B-unit swizzled
  unsigned short* ldsWal = lds + 64 * 512;
  unsigned short* packb  = lds + 2 * 64 * 512;  // 4 waves x 512 shorts (private)
  const int tid = threadIdx.x, lane = tid & 63, wv = tid >> 6;
  const int l15 = lane & 15, l4 = lane >> 4;
  const int g = blockIdx.x & 7, mem = blockIdx.x >> 3;
  const int colslice = mem * 64;
  unsigned* fl = flags + g * 64;
  unsigned* f0 = fl;           // 16 flags: h0 (2 per member)
  unsigned* f1 = fl + 16;      // 16 flags: h1

  // stage weight slices f32 -> bf16 LDS, 16B-unit swizzled
  for (int c = tid; c < 64 * 64; c += 256) {
    int row = c >> 6, u = c & 63, us = u ^ (row & 7);
    {
      const f32x4* p = (const f32x4*)(Waa + (size_t)(colslice + row) * HID + u * 8);
      *(bf16x8*)(ldsWaa + row * 512 + us * 8) = cvt8(p[0], p[1]);
    }
    {
      const f32x4* p = (const f32x4*)(Wal + (size_t)(colslice + row) * HID + u * 8);
      *(bf16x8*)(ldsWal + row * 512 + us * 8) = cvt8(p[0], p[1]);
    }
  }

  // per-wave geometry: each wave owns 2 col-tiles (32 cols)
  const int cb  = (wv & 1) * 2;                  // col-tile base within slice
  const int jc0 = colslice + cb * 16 + l15;      // out col, chain 0
  const int jc1 = jc0 + 16;                      // out col, chain 1
  const float ba0 = ba[jc0], ba1 = ba[jc1];
  const int wb0 = (cb * 16 + l15) * 512;         // LDS weight row base
  const int wb1 = wb0 + 16 * 512;
  const int swz = l15 & 7;
  const int aoff = l4 * 128 + l15 * 8;           // A-frag lane offset (shorts)
  // per-wave LDS pack region + offsets
  unsigned short* pk = packb + wv * 512;
  const int pl0 = ((l15 >> 3) + 0) * 128 + (l4 * 4) * 8 + (l15 & 7);
  const int pl1 = ((l15 >> 3) + 2) * 128 + (l4 * 4) * 8 + (l15 & 7);
  const int stbase = mem * 1024 + cb * 256 + lane * 8;  // wave's contiguous 1KB region
  const int brow = g * 16 + l4 * 4;
  unsigned short* h0g = h0buf + (size_t)g * (NSLOT * SLOT);
  unsigned short* h1g = h1buf + (size_t)g * (NSLOT * SLOT);
  __syncthreads();

#define WFRAG(W, wb, s) (*(const bf16x8*)((W) + (wb) + ((((s) * 4 + l4) ^ swz) * 8)))
#define LOAD16(arr, base)                                                         \
  _Pragma("unroll") for (int s = 0; s < 16; ++s)                                  \
    asm volatile("global_load_dwordx4 %0, %1, off sc0 sc1"                        \
                 : "=v"(arr[s]) : "v"((base) + s * 1024) : "memory");

  if (wv < 2) {
    // ================= h0 producers (waves 0,1) =================
    unsigned* myf = f0 + 2 * mem + (wv & 1);
    int idxA[4];
    unsigned cw0[4], cw1[4];
    { // prologue: idx(0) -> cw(0) gathers; then idx(1)
      int id0[4];
#pragma unroll
      for (int r = 0; r < 4; ++r)
        asm volatile("global_load_dword %0, %1, off"
                     : "=v"(id0[r]) : "v"(X + (size_t)(brow + r) * SEQ) : "memory");
      VMCNT0;
#pragma unroll
      for (int r = 0; r < 4; ++r) {
        const unsigned short* c0 = CW + (size_t)id0[r] * HID + jc0;
        asm volatile("global_load_ushort %0, %1, off" : "=v"(cw0[r]) : "v"(c0) : "memory");
        asm volatile("global_load_ushort %0, %1, off" : "=v"(cw1[r]) : "v"(c0 + 16) : "memory");
      }
#pragma unroll
      for (int r = 0; r < 4; ++r)
        asm volatile("global_load_dword %0, %1, off"
                     : "=v"(idxA[r]) : "v"(X + (size_t)(brow + r) * SEQ + 1) : "memory");
    }
    for (int t = 0; t < SEQ; ++t) {
      poll2(f0, f1, (unsigned)t, (unsigned)(t >= 2 ? t - 2 : 0));  // drains all prefetches
      bf16x8 a0[16];
      const char* pa0 = (const char*)(h0g + ((t + 3) & 3) * SLOT + aoff);
      LOAD16(a0, pa0)
      VMCNT0; SCHED0;
      f32x4 acc0 = (f32x4){0.f, 0.f, 0.f, 0.f};
      f32x4 acc1 = (f32x4){0.f, 0.f, 0.f, 0.f};
#pragma unroll
      for (int s = 0; s < 16; ++s) {
        bf16x8 a = a0[s];
        acc0 = mfma16(a, WFRAG(ldsWaa, wb0, s), acc0);
        acc1 = mfma16(a, WFRAG(ldsWaa, wb1, s), acc1);
      }
#pragma unroll
      for (int r = 0; r < 4; ++r) {
        float v0 = fast_tanh(acc0[r] + bf2f((unsigned short)cw0[r]) + ba0);
        float v1 = fast_tanh(acc1[r] + bf2f((unsigned short)cw1[r]) + ba1);
        pk[pl0 + r * 8] = (unsigned short)f2bf(v0);
        pk[pl1 + r * 8] = (unsigned short)f2bf(v1);
      }
      LGKM0; SCHED0;                       // wave-private pack complete
      bf16x8 ov = *(const bf16x8*)(pk + lane * 8);
      st16(h0g + (t & 3) * SLOT + stbase, ov);
      VMCNT0;                              // store at coherent point
      if (lane == 0) sig(myf, (unsigned)(t + 1));
      // tail prefetches: cw(t+1) via idxA (=X(t+1), drained), then idxA <- X(t+2)
#pragma unroll
      for (int r = 0; r < 4; ++r) {
        const unsigned short* c0 = CW + (size_t)idxA[r] * HID + jc0;
        asm volatile("global_load_ushort %0, %1, off" : "=v"(cw0[r]) : "v"(c0) : "memory");
        asm volatile("global_load_ushort %0, %1, off" : "=v"(cw1[r]) : "v"(c0 + 16) : "memory");
      }
      const int tp = (t + 2 < SEQ) ? t + 2 : SEQ - 1;
#pragma unroll
      for (int r = 0; r < 4; ++r)
        asm volatile("global_load_dword %0, %1, off"
                     : "=v"(idxA[r]) : "v"(X + (size_t)(brow + r) * SEQ + tp) : "memory");
    }
  } else {
    // ================= h1 producers (waves 2,3): step t computes h1(t-1) =========
    unsigned* myf = f1 + 2 * mem + (wv & 1);
    for (int t = 0; t <= SEQ; ++t) {
      poll2(f0, f1, (unsigned)t, (unsigned)t);
      if (t >= 1) {
        bf16x8 a1[16], a2[16];
        const char* pa1 = (const char*)(h0g + ((t + 3) & 3) * SLOT + aoff);  // h0(t-1)
        const char* pa2 = (const char*)(h1g + ((t + 2) & 3) * SLOT + aoff);  // h1(t-2)
        LOAD16(a1, pa1)
        LOAD16(a2, pa2)
        VMCNT16; SCHED0;                   // a1 ready
        f32x4 acc0 = (f32x4){0.f, 0.f, 0.f, 0.f};
        f32x4 acc1 = (f32x4){0.f, 0.f, 0.f, 0.f};
#pragma unroll
        for (int s = 0; s < 16; ++s) {
          bf16x8 a = a1[s];
          acc0 = mfma16(a, WFRAG(ldsWal, wb0, s), acc0);
          acc1 = mfma16(a, WFRAG(ldsWal, wb1, s), acc1);
        }
        VMCNT0; SCHED0;                    // a2 ready
#pragma unroll
        for (int s = 0; s < 16; ++s) {
          bf16x8 a = a2[s];
          acc0 = mfma16(a, WFRAG(ldsWaa, wb0, s), acc0);
          acc1 = mfma16(a, WFRAG(ldsWaa, wb1, s), acc1);
        }
#pragma unroll
        for (int r = 0; r < 4; ++r) {
          float v0 = fast_tanh(acc0[r] + ba0);
          float v1 = fast_tanh(acc1[r] + ba1);
          pk[pl0 + r * 8] = (unsigned short)f2bf(v0);
          pk[pl1 + r * 8] = (unsigned short)f2bf(v1);
        }
        LGKM0; SCHED0;
        bf16x8 ov = *(const bf16x8*)(pk + lane * 8);
        st16(h1g + ((t + 3) & 3) * SLOT + stbase, ov);   // h1(t-1) -> slot (t-1)%4
        VMCNT0;
      }
      if (lane == 0) sig(myf, (unsigned)(t + 1));
    }
  }
#undef LOAD16
#undef WFRAG
}

// ---- out = h1_final @ W_out.T + b_out  (M=128, N=32000, K=512) ----
__global__ void __launch_bounds__(256) k_out(const float* __restrict__ Wout,
                                             const float* __restrict__ bout,
                                             const unsigned short* __restrict__ h1buf,
                                             float* __restrict__ out) {
  const int tid = threadIdx.x, lane = tid & 63, wv = tid >> 6;
  const int l15 = lane & 15, l4 = lane >> 4;
  const int col = blockIdx.x * 64 + wv * 16 + l15;
  const float bo = bout[col];
  f32x4 acc[8];
#pragma unroll
  for (int rt = 0; rt < 8; ++rt) acc[rt] = (f32x4){0.f, 0.f, 0.f, 0.f};
  const int aoff = l4 * 128 + l15 * 8;
#pragma unroll 4
  for (int s = 0; s < 16; ++s) {
    const f32x4* bp = (const f32x4*)(Wout + (size_t)col * HID + s * 32 + l4 * 8);
    bf16x8 b = cvt8(bp[0], bp[1]);
#pragma unroll
    for (int rt = 0; rt < 8; ++rt) {
      // group rt, slot 3 (= 511 % 4) holds final h1(511)
      const unsigned short* ap = h1buf + (size_t)rt * (NSLOT * SLOT) + 3 * SLOT + aoff + s * 512;
      acc[rt] = mfma16(*(const bf16x8*)ap, b, acc[rt]);
    }
  }
#pragma unroll
  for (int rt = 0; rt < 8; ++rt) {
#pragma unroll
    for (int r = 0; r < 4; ++r) {
      int row = rt * 16 + l4 * 4 + r;
      out[(size_t)row * VOCAB + col] = acc[rt][r] + bo;
    }
  }
}

extern "C" void kernel_launch(void* const* d_in, const int* in_sizes, int n_in,
                              void* d_out, int out_size, void* d_ws, size_t ws_size,
                              hipStream_t stream) {
  const int*   X    = (const int*)d_in[0];
  const float* C    = (const float*)d_in[1];
  const float* Wax  = (const float*)d_in[2];
  const float* Waa  = (const float*)d_in[3];
  const float* Wal  = (const float*)d_in[4];
  const float* ba   = (const float*)d_in[5];
  const float* Wout = (const float*)d_in[6];
  const float* bout = (const float*)d_in[7];
  float* out = (float*)d_out;
  char* ws = (char*)d_ws;
  (void)in_sizes; (void)n_in; (void)out_size;

  const size_t cw_bytes = (size_t)VOCAB * HID * 2;          // 32,768,000
  const size_t h_bytes  = 8ull * NSLOT * SLOT * 2;          // 524,288 per tensor
  const size_t off_h0 = cw_bytes;
  const size_t off_h1 = off_h0 + h_bytes;
  const size_t off_fl = off_h1 + h_bytes;
  const size_t fl_bytes = 8 * 64 * 4;                       // 2 KB
  if (ws_size < off_fl + fl_bytes) return;

  unsigned short* CWp = (unsigned short*)(ws);
  unsigned short* h0  = (unsigned short*)(ws + off_h0);
  unsigned short* h1  = (unsigned short*)(ws + off_h1);
  unsigned*       fl  = (unsigned*)(ws + off_fl);

  const int zero_words = (int)((2 * h_bytes + fl_bytes) / 4);
  hipLaunchKernelGGL(k_init, dim3((zero_words + 255) / 256), dim3(256), 0, stream,
                     (unsigned*)(ws + off_h0), zero_words);
  hipLaunchKernelGGL(k_cw, dim3(VOCAB / 64), dim3(256), 0, stream, C, Wax, CWp);
  hipFuncSetAttribute((const void*)k_scan, hipFuncAttributeMaxDynamicSharedMemorySize, 135168);
  hipLaunchKernelGGL(k_scan, dim3(64), dim3(256), 135168, stream,
                     X, Waa, Wal, ba, CWp, h0, h1, fl);
  hipLaunchKernelGGL(k_out, dim3(VOCAB / 64), dim3(256), 0, stream, Wout, bout, h1, out);
}